// Round 1
// baseline (638.655 us; speedup 1.0000x reference)
//
#include <hip/hip_runtime.h>

#define C 64

typedef float fx4 __attribute__((ext_vector_type(4)));

// ---------------------------------------------------------------------------
// K1: per-node dot d[i] = dot(x[i,:], lin_w), plus learned[i] = lin_b init.
// Four nodes per wave: 16 lanes/node, float4 each (16 lanes * 16B = 256B row).
// Wave reads 1024B contiguous. Reduce via 4 xor-shuffles within 16-lane group.
// NOTE: x flows through L2/L3 here; gather_kernel re-reads it — keep cached.
// ---------------------------------------------------------------------------
__global__ void dot_kernel(const float4* __restrict__ x4,
                           const float4* __restrict__ w4,
                           const float* __restrict__ lin_b,
                           float* __restrict__ d,
                           float* __restrict__ learned, int n) {
    int gtid = blockIdx.x * blockDim.x + threadIdx.x;
    int wave = gtid >> 6;
    int lane = threadIdx.x & 63;
    int sub  = lane >> 4;          // which node within the wave (0..3)
    int sl   = lane & 15;          // lane within node group
    int node = wave * 4 + sub;
    if (node >= n) return;
    float4 v = x4[(size_t)node * 16 + sl];
    float4 w = w4[sl];
    float t = v.x * w.x + v.y * w.y + v.z * w.z + v.w * w.w;
    t += __shfl_xor(t, 8, 64);
    t += __shfl_xor(t, 4, 64);
    t += __shfl_xor(t, 2, 64);
    t += __shfl_xor(t, 1, 64);
    if (sl == 0) {
        d[node] = t;
        learned[node] = lin_b[0];  // self-loop message contributes exactly lin_b
    }
}

// ---------------------------------------------------------------------------
// K2: histogram + rank capture + learned scatter.
//   rank[e]   = order of edge e among edges sharing dst  (from atomic return)
//   count[t] += 1
//   learned[t] += d[s]-d[t]+lin_b          (only consumed for t >= FIRST)
// ---------------------------------------------------------------------------
__global__ void hist_kernel(const int* __restrict__ ei,
                            const float* __restrict__ d,
                            const float* __restrict__ lin_b,
                            float* __restrict__ learned,
                            int* __restrict__ count,
                            int* __restrict__ rank,
                            int n, int first) {
    int e = blockIdx.x * blockDim.x + threadIdx.x;
    if (e >= n) return;
    int t = ei[n + e];
    rank[e] = atomicAdd(&count[t], 1);
    if (t >= first) {
        int s = ei[e];
        atomicAdd(&learned[t], d[s] - d[t] + lin_b[0]);
    }
}

// ---------------------------------------------------------------------------
// Exclusive scan of count[] -> off[] (2 kernels; block offsets stay in
// partial[] and are folded in by consumers). n = nb*256 exactly.
// ---------------------------------------------------------------------------
__global__ void scan1_kernel(const int* __restrict__ count,
                             int* __restrict__ off,
                             int* __restrict__ partial) {
    __shared__ int sh[256];
    int tid = threadIdx.x;
    int gid = blockIdx.x * 256 + tid;
    int v = count[gid];
    sh[tid] = v;
    __syncthreads();
    for (int o = 1; o < 256; o <<= 1) {
        int t = (tid >= o) ? sh[tid - o] : 0;
        __syncthreads();
        sh[tid] += t;
        __syncthreads();
    }
    off[gid] = sh[tid] - v;
    if (tid == 255) partial[blockIdx.x] = sh[255];
}

__global__ void scan2_kernel(int* __restrict__ partial, int nb) {
    __shared__ int sh[256];
    int tid = threadIdx.x;
    int chunk = nb / 256;
    int base = tid * chunk;
    int sum = 0;
    for (int k = 0; k < chunk; ++k) sum += partial[base + k];
    sh[tid] = sum;
    __syncthreads();
    for (int o = 1; o < 256; o <<= 1) {
        int t = (tid >= o) ? sh[tid - o] : 0;
        __syncthreads();
        sh[tid] += t;
        __syncthreads();
    }
    int running = sh[tid] - sum;
    for (int k = 0; k < chunk; ++k) {
        int v = partial[base + k];
        partial[base + k] = running;
        running += v;
    }
}

// ---------------------------------------------------------------------------
// K3: reorder edges into CSR buckets (atomic-free; uses captured rank).
//   score[e] = base(e) + (e>=FIRST ? learned[e] : 0)   [indexed by EDGE pos]
//   final offset = off[t] + partial[t>>8]  (scan3 folded in here)
// ---------------------------------------------------------------------------
__global__ void reorder_kernel(const int* __restrict__ ei,
                               const float* __restrict__ learned,
                               const int* __restrict__ off,
                               const int* __restrict__ partial,
                               const int* __restrict__ rank,
                               int2* __restrict__ srcscore,
                               const float* __restrict__ w1,
                               const float* __restrict__ w2,
                               const float* __restrict__ w3,
                               int n, int first) {
    int e = blockIdx.x * blockDim.x + threadIdx.x;
    if (e >= n) return;
    float score;
    if (e < first) {
        score = w1[0];
    } else {
        float base = (((e - first) & 1) == 0) ? w2[0] : w3[0];
        score = base + learned[e];
    }
    int s = ei[e];
    int t = ei[n + e];
    int pos = off[t] + partial[t >> 8] + rank[e];
    srcscore[pos] = make_int2(s, __float_as_int(score));
}

// ---------------------------------------------------------------------------
// K4: gather. Four nodes per wave (16 lanes x float4 per node):
//   out[i,:] = relu(sum_j x[src_j,:]*score_j)
// Changes vs prior version:
//  - srcscore entries for a node are prefetched 16-at-a-time with one
//    coalesced predicated load, then broadcast via __shfl: per-edge serial
//    latency drops from 2 global-load latencies to 1 for degree >= 2.
//  - out stores are NONTEMPORAL: out is 268 MB of single-use streaming
//    writes; bypassing L3 keeps x (268 MB, just streamed by dot_kernel)
//    resident so the random x-row gathers hit Infinity Cache.
//  - scan3 folded in: beg/end add partial[blk].
// ---------------------------------------------------------------------------
__global__ void gather_kernel(const float4* __restrict__ x4,
                              const int* __restrict__ off,
                              const int* __restrict__ partial,
                              const int2* __restrict__ srcscore,
                              float4* __restrict__ out4, int n) {
    int gtid = blockIdx.x * blockDim.x + threadIdx.x;
    int wave = gtid >> 6;
    int lane = threadIdx.x & 63;
    int sub  = lane >> 4;
    int sl   = lane & 15;
    int node = wave * 4 + sub;
    if (node >= n) return;
    int beg = off[node] + partial[node >> 8];
    int end = (node + 1 < n) ? (off[node + 1] + partial[(node + 1) >> 8]) : n;
    float4 acc = make_float4(0.f, 0.f, 0.f, 0.f);
    int base = sub << 4;
    for (int j0 = beg; j0 < end; j0 += 16) {
        int rem = end - j0;
        int m = (rem < 16) ? rem : 16;
        int2 p = make_int2(0, 0);
        if (sl < m) p = srcscore[j0 + sl];      // one coalesced batch load
        for (int k = 0; k < m; ++k) {
            int   src = __shfl(p.x, base + k, 64);
            float s   = __int_as_float(__shfl(p.y, base + k, 64));
            float4 v = x4[(size_t)src * 16 + sl];
            acc.x += v.x * s;
            acc.y += v.y * s;
            acc.z += v.z * s;
            acc.w += v.w * s;
        }
    }
    acc.x = fmaxf(acc.x, 0.f);
    acc.y = fmaxf(acc.y, 0.f);
    acc.z = fmaxf(acc.z, 0.f);
    acc.w = fmaxf(acc.w, 0.f);
    fx4 av;
    av.x = acc.x; av.y = acc.y; av.z = acc.z; av.w = acc.w;
    __builtin_nontemporal_store(av, (fx4*)&out4[(size_t)node * 16 + sl]);
}

extern "C" void kernel_launch(void* const* d_in, const int* in_sizes, int n_in,
                              void* d_out, int out_size, void* d_ws, size_t ws_size,
                              hipStream_t stream) {
    const float* x     = (const float*)d_in[0];   // [N, 64]
    const float* lin_w = (const float*)d_in[1];   // [1, 64]
    const float* lin_b = (const float*)d_in[2];   // [1]
    const float* w1    = (const float*)d_in[3];
    const float* w2    = (const float*)d_in[4];
    const float* w3    = (const float*)d_in[5];
    const int*   ei    = (const int*)d_in[6];     // [2, N]
    float* out = (float*)d_out;                   // [N, 64]

    const int n = in_sizes[0] / C;                // nodes == edges (1048576)
    const int first = n / 3;
    const int nb = n / 256;                       // 4096

    // workspace: 7n ints/floats + nb
    float* d_dot    = (float*)d_ws;               // n
    float* learned  = d_dot + n;                  // n
    int*   count    = (int*)(learned + n);        // n
    int*   off      = count + n;                  // n
    int*   rank     = off + n;                    // n
    int2*  srcscore = (int2*)(rank + n);          // n int2
    int*   partial  = (int*)(srcscore + n);       // nb

    hipMemsetAsync(count, 0, (size_t)n * sizeof(int), stream);

    // wave serves 4 nodes -> n/4 waves -> n*16 threads total -> n/16 blocks
    dot_kernel<<<dim3(n / 16), dim3(256), 0, stream>>>(
        (const float4*)x, (const float4*)lin_w, lin_b, d_dot, learned, n);
    hist_kernel<<<dim3(nb), dim3(256), 0, stream>>>(ei, d_dot, lin_b, learned,
                                                    count, rank, n, first);
    scan1_kernel<<<dim3(nb), dim3(256), 0, stream>>>(count, off, partial);
    scan2_kernel<<<dim3(1), dim3(256), 0, stream>>>(partial, nb);
    reorder_kernel<<<dim3(nb), dim3(256), 0, stream>>>(ei, learned, off, partial,
                                                       rank, srcscore, w1, w2, w3,
                                                       n, first);
    gather_kernel<<<dim3(n / 16), dim3(256), 0, stream>>>(
        (const float4*)x, off, partial, srcscore, (float4*)out, n);
}

// Round 2
// 635.238 us; speedup vs baseline: 1.0054x; 1.0054x over previous
//
#include <hip/hip_runtime.h>

#define C 64

typedef float fx4 __attribute__((ext_vector_type(4)));

// ---------------------------------------------------------------------------
// K1: FUSED dot + histogram/rank.
//  dot part  : d[i] = dot(x[i,:], lin_w). Four nodes per wave: 16 lanes/node,
//              float4 each (16 lanes * 16B = 256B row) -> wave reads 1024B
//              contiguous. Reduce via 4 xor-shuffles within 16-lane group.
//  hist part : threads with gtid < n handle edge e = gtid:
//              rank[e] = atomicAdd(&count[dst], 1).
//  Rationale: count/rank does NOT depend on d, so it fuses with the dot pass.
//  dot is BW-bound streaming, hist is atomic/latency-bound -> co-scheduled
//  waves overlap (time ~= max, not sum).
//  NOTE: x flows through L2/L3 here; gather re-reads it — keep cached.
// ---------------------------------------------------------------------------
__global__ void dot_hist_kernel(const float4* __restrict__ x4,
                                const float4* __restrict__ w4,
                                const int* __restrict__ ei,
                                float* __restrict__ d,
                                int* __restrict__ count,
                                int* __restrict__ rank,
                                int n) {
    int gtid = blockIdx.x * blockDim.x + threadIdx.x;

    // --- hist part (first n threads = blocks 0..n/256-1): issue early so the
    // atomic round-trips overlap the dot loads below.
    if (gtid < n) {
        int t = ei[n + gtid];
        rank[gtid] = atomicAdd(&count[t], 1);
    }

    // --- dot part
    int wave = gtid >> 6;
    int lane = threadIdx.x & 63;
    int sub  = lane >> 4;          // which node within the wave (0..3)
    int sl   = lane & 15;          // lane within node group
    int node = wave * 4 + sub;
    if (node >= n) return;
    float4 v = x4[(size_t)node * 16 + sl];
    float4 w = w4[sl];
    float t = v.x * w.x + v.y * w.y + v.z * w.z + v.w * w.w;
    t += __shfl_xor(t, 8, 64);
    t += __shfl_xor(t, 4, 64);
    t += __shfl_xor(t, 2, 64);
    t += __shfl_xor(t, 1, 64);
    if (sl == 0) d[node] = t;
}

// ---------------------------------------------------------------------------
// K2: FUSED learned-scatter + scan1.
//  scatter : learned[t] += d[s]-d[t]+lin_b   (t >= first only; learned was
//            zero-initialized by the memset; the self-loop lin_b and the
//            per-node base are added in reorder instead).
//  scan1   : block-local exclusive scan of count[] -> off[], block sums to
//            partial[]. Scatter is latency-bound, scan is a tiny LDS kernel;
//            independent arrays, so they fuse race-free.
// ---------------------------------------------------------------------------
__global__ void scatter_scan1_kernel(const int* __restrict__ ei,
                                     const float* __restrict__ d,
                                     const float* __restrict__ lin_b,
                                     float* __restrict__ learned,
                                     const int* __restrict__ count,
                                     int* __restrict__ off,
                                     int* __restrict__ partial,
                                     int n, int first) {
    __shared__ int sh[256];
    int tid = threadIdx.x;
    int gid = blockIdx.x * 256 + tid;

    // scatter (issue first: atomics drain while the scan runs)
    int t = ei[n + gid];
    if (t >= first) {
        int s = ei[gid];
        atomicAdd(&learned[t], d[s] - d[t] + lin_b[0]);
    }

    // scan1
    int v = count[gid];
    sh[tid] = v;
    __syncthreads();
    for (int o = 1; o < 256; o <<= 1) {
        int tt = (tid >= o) ? sh[tid - o] : 0;
        __syncthreads();
        sh[tid] += tt;
        __syncthreads();
    }
    off[gid] = sh[tid] - v;
    if (tid == 255) partial[blockIdx.x] = sh[255];
}

__global__ void scan2_kernel(int* __restrict__ partial, int nb) {
    __shared__ int sh[256];
    int tid = threadIdx.x;
    int chunk = nb / 256;
    int base = tid * chunk;
    int sum = 0;
    for (int k = 0; k < chunk; ++k) sum += partial[base + k];
    sh[tid] = sum;
    __syncthreads();
    for (int o = 1; o < 256; o <<= 1) {
        int t = (tid >= o) ? sh[tid - o] : 0;
        __syncthreads();
        sh[tid] += t;
        __syncthreads();
    }
    int running = sh[tid] - sum;
    for (int k = 0; k < chunk; ++k) {
        int v = partial[base + k];
        partial[base + k] = running;
        running += v;
    }
}

// ---------------------------------------------------------------------------
// K3: reorder edges into CSR buckets (atomic-free; uses captured rank).
//   score[e] = w1                                  , e <  first
//            = (w2|w3) + lin_b + learned[e]        , e >= first
//   (lin_b is the self-loop message; learned[] was zero-initialized.)
//   final offset = off[t] + partial[t>>8]  (scan3 folded in here)
// ---------------------------------------------------------------------------
__global__ void reorder_kernel(const int* __restrict__ ei,
                               const float* __restrict__ learned,
                               const int* __restrict__ off,
                               const int* __restrict__ partial,
                               const int* __restrict__ rank,
                               int2* __restrict__ srcscore,
                               const float* __restrict__ lin_b,
                               const float* __restrict__ w1,
                               const float* __restrict__ w2,
                               const float* __restrict__ w3,
                               int n, int first) {
    int e = blockIdx.x * blockDim.x + threadIdx.x;
    if (e >= n) return;
    float score;
    if (e < first) {
        score = w1[0];
    } else {
        float base = (((e - first) & 1) == 0) ? w2[0] : w3[0];
        score = base + lin_b[0] + learned[e];
    }
    int s = ei[e];
    int t = ei[n + e];
    int pos = off[t] + partial[t >> 8] + rank[e];
    srcscore[pos] = make_int2(s, __float_as_int(score));
}

// ---------------------------------------------------------------------------
// K4: gather. Four nodes per wave (16 lanes x float4 per node):
//   out[i,:] = relu(sum_j x[src_j,:]*score_j)
//  - srcscore entries for a node are prefetched 16-at-a-time with one
//    coalesced predicated load, then broadcast via __shfl.
//  - out stores are NONTEMPORAL: out is 268 MB of single-use streaming
//    writes; bypassing L3 keeps x (268 MB, streamed by K1) resident so the
//    random x-row gathers hit Infinity Cache.
//  - scan3 folded in: beg/end add partial[blk].
// ---------------------------------------------------------------------------
__global__ void gather_kernel(const float4* __restrict__ x4,
                              const int* __restrict__ off,
                              const int* __restrict__ partial,
                              const int2* __restrict__ srcscore,
                              float4* __restrict__ out4, int n) {
    int gtid = blockIdx.x * blockDim.x + threadIdx.x;
    int wave = gtid >> 6;
    int lane = threadIdx.x & 63;
    int sub  = lane >> 4;
    int sl   = lane & 15;
    int node = wave * 4 + sub;
    if (node >= n) return;
    int beg = off[node] + partial[node >> 8];
    int end = (node + 1 < n) ? (off[node + 1] + partial[(node + 1) >> 8]) : n;
    float4 acc = make_float4(0.f, 0.f, 0.f, 0.f);
    int base = sub << 4;
    for (int j0 = beg; j0 < end; j0 += 16) {
        int rem = end - j0;
        int m = (rem < 16) ? rem : 16;
        int2 p = make_int2(0, 0);
        if (sl < m) p = srcscore[j0 + sl];      // one coalesced batch load
        for (int k = 0; k < m; ++k) {
            int   src = __shfl(p.x, base + k, 64);
            float s   = __int_as_float(__shfl(p.y, base + k, 64));
            float4 v = x4[(size_t)src * 16 + sl];
            acc.x += v.x * s;
            acc.y += v.y * s;
            acc.z += v.z * s;
            acc.w += v.w * s;
        }
    }
    acc.x = fmaxf(acc.x, 0.f);
    acc.y = fmaxf(acc.y, 0.f);
    acc.z = fmaxf(acc.z, 0.f);
    acc.w = fmaxf(acc.w, 0.f);
    fx4 av;
    av.x = acc.x; av.y = acc.y; av.z = acc.z; av.w = acc.w;
    __builtin_nontemporal_store(av, (fx4*)&out4[(size_t)node * 16 + sl]);
}

extern "C" void kernel_launch(void* const* d_in, const int* in_sizes, int n_in,
                              void* d_out, int out_size, void* d_ws, size_t ws_size,
                              hipStream_t stream) {
    const float* x     = (const float*)d_in[0];   // [N, 64]
    const float* lin_w = (const float*)d_in[1];   // [1, 64]
    const float* lin_b = (const float*)d_in[2];   // [1]
    const float* w1    = (const float*)d_in[3];
    const float* w2    = (const float*)d_in[4];
    const float* w3    = (const float*)d_in[5];
    const int*   ei    = (const int*)d_in[6];     // [2, N]
    float* out = (float*)d_out;                   // [N, 64]

    const int n = in_sizes[0] / C;                // nodes == edges (1048576)
    const int first = n / 3;
    const int nb = n / 256;                       // 4096

    // workspace: 7n ints/floats + nb   (learned and count adjacent -> one memset)
    float* d_dot    = (float*)d_ws;               // n
    float* learned  = d_dot + n;                  // n  (zero = bits 0 for f32)
    int*   count    = (int*)(learned + n);        // n
    int*   off      = count + n;                  // n
    int*   rank     = off + n;                    // n
    int2*  srcscore = (int2*)(rank + n);          // n int2
    int*   partial  = (int*)(srcscore + n);       // nb

    hipMemsetAsync(learned, 0, (size_t)2 * n * sizeof(int), stream);

    // K1: dot (n/4 waves -> n*16 threads) + count/rank hist (first n threads)
    dot_hist_kernel<<<dim3(n / 16), dim3(256), 0, stream>>>(
        (const float4*)x, (const float4*)lin_w, ei, d_dot, count, rank, n);
    // K2: learned scatter + scan1
    scatter_scan1_kernel<<<dim3(nb), dim3(256), 0, stream>>>(
        ei, d_dot, lin_b, learned, count, off, partial, n, first);
    scan2_kernel<<<dim3(1), dim3(256), 0, stream>>>(partial, nb);
    reorder_kernel<<<dim3(nb), dim3(256), 0, stream>>>(ei, learned, off, partial,
                                                       rank, srcscore, lin_b,
                                                       w1, w2, w3, n, first);
    gather_kernel<<<dim3(n / 16), dim3(256), 0, stream>>>(
        (const float4*)x, off, partial, srcscore, (float4*)out, n);
}